// Round 1
// baseline (179.500 us; speedup 1.0000x reference)
//
#include <hip/hip_runtime.h>
#include <stdint.h>

// Problem constants (fixed by reference setup_inputs)
#define NPOS 512   // N
#define NH   64    // H
#define NM   1024  // M
#define NB   256   // B
#define NM1  511   // N-1

typedef __attribute__((ext_vector_type(8)))  short bf16x8;
typedef __attribute__((ext_vector_type(16))) float f32x16;
typedef __attribute__((ext_vector_type(4)))  float f32x4;
typedef __attribute__((ext_vector_type(4)))  int   i32x4;

#if __has_builtin(__builtin_amdgcn_exp2f)
#define EXP2F(x) __builtin_amdgcn_exp2f(x)
#else
#define EXP2F(x) __expf((x) * 0.69314718055994531f)
#endif

__device__ __forceinline__ unsigned short f2bf(float x) {
    unsigned u = __float_as_uint(x);
    u = (u + 0x7FFFu + ((u >> 16) & 1u)) >> 16;   // RNE
    return (unsigned short)u;
}
__device__ __forceinline__ int pack2(unsigned short a, unsigned short b) {
    return (int)a | ((int)b << 16);
}

// ---------------- kA: fused prep = {k0 seq->bf16 + zero out, k1a BnT softmax,
//                  k1c plusT transpose}. 272 blocks x 256 thr. ----------------
__global__ __launch_bounds__(256, 4)
void kA_prep(const float* __restrict__ seq, const float* __restrict__ Bl,
             const float* __restrict__ mem,
             unsigned short* __restrict__ seq_bf, float* __restrict__ BnT,
             float* __restrict__ plusT, float* __restrict__ out) {
    const int bid = blockIdx.x, t = threadIdx.x;
    if (bid < 128) {
        // --- k0: sequences fp32 -> bf16 (exact for +/-1) ---
        if (bid == 0 && t == 0) out[0] = 0.f;
        int idx = (bid * 256 + t) * 4;
        f32x4 v = *(const f32x4*)(seq + idx);
        int2 o;
        o.x = pack2(f2bf(v.x), f2bf(v.y));
        o.y = pack2(f2bf(v.z), f2bf(v.w));
        *(int2*)(seq_bf + idx) = o;
    } else if (bid < 144) {
        // --- k1a: Bn = softmax(B_logits, axis=-1), stored transposed ---
        const int h = (bid - 128) * 4 + (t >> 6), l = t & 63;
        float v[8]; float mx = -1e30f;
#pragma unroll
        for (int j = 0; j < 8; j++) { v[j] = Bl[h * NPOS + l + 64 * j]; mx = fmaxf(mx, v[j]); }
#pragma unroll
        for (int o = 32; o; o >>= 1) mx = fmaxf(mx, __shfl_xor(mx, o));
        float s = 0.f;
#pragma unroll
        for (int j = 0; j < 8; j++) { v[j] = __expf(v[j] - mx); s += v[j]; }
#pragma unroll
        for (int o = 32; o; o >>= 1) s += __shfl_xor(s, o);
        float r = 1.0f / s;
#pragma unroll
        for (int j = 0; j < 8; j++) BnT[(l + 64 * j) * NH + h] = v[j] * r;
    } else {
        // --- k1c: plusT[n][m] via LDS 64x64 tile transpose ---
        __shared__ float sT[64][65];
        const int bb = bid - 144;
        const int mt = bb >> 3, nt = bb & 7;
        const int rr = t >> 2, cc = t & 3;
        const float* src = mem + (size_t)(mt * 64 + rr) * NPOS + nt * 64 + cc * 16;
#pragma unroll
        for (int j = 0; j < 4; j++) {
            f32x4 v = *(const f32x4*)(src + j * 4);
            sT[rr][cc * 16 + j * 4 + 0] = (v.x > 0.f) ? 1.f : 0.f;
            sT[rr][cc * 16 + j * 4 + 1] = (v.y > 0.f) ? 1.f : 0.f;
            sT[rr][cc * 16 + j * 4 + 2] = (v.z > 0.f) ? 1.f : 0.f;
            sT[rr][cc * 16 + j * 4 + 3] = (v.w > 0.f) ? 1.f : 0.f;
        }
        __syncthreads();
        float* dst = plusT + (size_t)(nt * 64 + rr) * NM + mt * 64 + cc * 16;
#pragma unroll
        for (int j = 0; j < 4; j++) {
            f32x4 o;
            o.x = sT[cc * 16 + j * 4 + 0][rr];
            o.y = sT[cc * 16 + j * 4 + 1][rr];
            o.z = sT[cc * 16 + j * 4 + 2][rr];
            o.w = sT[cc * 16 + j * 4 + 3][rr];
            *(f32x4*)(dst + j * 4) = o;
        }
    }
}

// ---------------- k1b: phi_mu[m,h] = sum_n Bn[h,n]*memory[m,n] -> bf16 -------
// 512 blocks x 2 m-rows, 4 independent fma chains. PRE-SCALED by log2(e).
__global__ __launch_bounds__(256, 4)
void k1b_phimu(const float* __restrict__ BnT, const float* __restrict__ mem,
               unsigned short* __restrict__ phimu) {
    const int m0 = blockIdx.x * 2, t = threadIdx.x;
    __shared__ float mrow[2][NPOS];
    __shared__ float part[2][256];
    {
        int row = t >> 7, c = (t & 127) * 4;
        *(f32x4*)(&mrow[row][c]) = *(const f32x4*)(mem + (size_t)(m0 + row) * NPOS + c);
    }
    __syncthreads();
    const int h = t & 63, seg = t >> 6;
    float a[2] = {0.f, 0.f};
    float b2[2] = {0.f, 0.f};
    const float* bp = BnT + seg * 128 * NH + h;
#pragma unroll 8
    for (int nn = 0; nn < 128; nn += 2) {
        float x0 = bp[nn * NH], x1 = bp[(nn + 1) * NH];
#pragma unroll
        for (int row = 0; row < 2; row++) {
            a[row]  = fmaf(x0, mrow[row][seg * 128 + nn], a[row]);
            b2[row] = fmaf(x1, mrow[row][seg * 128 + nn + 1], b2[row]);
        }
    }
#pragma unroll
    for (int row = 0; row < 2; row++) part[row][t] = a[row] + b2[row];
    __syncthreads();
    if (t < 64) {
#pragma unroll
        for (int row = 0; row < 2; row++) {
            float s = (part[row][t] + part[row][t + 64]) + (part[row][t + 128] + part[row][t + 192]);
            phimu[(m0 + row) * NH + t] = f2bf(s * 1.4426950408889634f);  // * log2(e)
        }
    }
}

// ---------------- k23: FUSED hat_phi + retrieval softmax + BCE ---------------
// grid 1022: block = (n, b-half). Each block does 128 of the 256 b rows.
// LDS 32 KB -> 4 blocks/CU co-resident (2x occupancy vs the 511-block version).
// E = exp(masked A_logits[n]) staging is duplicated across the 2 b-halves
// (cheap); MFMA / exp / accumulate work is partitioned, not duplicated.
// Paired blocks (same n) are grid-adjacent -> A-row re-read hits L3.
__global__ __launch_bounds__(256, 4)
void k23_fused(const float* __restrict__ Al, const unsigned short* __restrict__ seq_bf,
               const unsigned short* __restrict__ phimu, const float* __restrict__ plusT,
               const float* __restrict__ seq, float* __restrict__ out) {
    __shared__ __align__(16) unsigned short s_lds[128 * 72];  // S tile -> q tile
    __shared__ __align__(16) unsigned short e_lds[64 * 72];   // E tile -> dsum/nsum
    __shared__ float z_lds[64];                               // row sums Z[h] -> wave partials
    __shared__ float s_plus[NM];

    const int t = threadIdx.x;
    const int bid = blockIdx.x;
    const int n = NM1 - (bid >> 1);              // n in 1..511, big n first
    const int boff = (bid & 1) << 7;             // which 128-row b-half
    const int ksteps = (n + 63) >> 6;
    const int wv = t >> 6, lane = t & 63, half = lane >> 5, r = lane & 31;

    if (t < 64) z_lds[t] = 0.f;
    // stage plus row early (independent of phase 1)
    *(f32x4*)(s_plus + t * 4) = *(const f32x4*)(plusT + (size_t)n * NM + t * 4);

    // ================= phase 1: hat_phi tile (128 b x 64 h) =================
    const int eh = t >> 2, ei = (t & 3) * 16;
    const float* arow = Al + ((size_t)n * NH + eh) * NPOS + ei;
    const int srow = t & 127, skh = (t >> 7) * 32;   // 2 threads stage one 64-wide S row
    const unsigned short* srcS = seq_bf + (size_t)(boff + srow) * NPOS + skh;

    f32x16 acc0, acc1;
#pragma unroll
    for (int i = 0; i < 16; i++) { acc0[i] = 0.f; acc1[i] = 0.f; }

    f32x4 ea[4]; i32x4 sa[4];
#pragma unroll
    for (int g = 0; g < 4; g++) ea[g] = *(const f32x4*)(arow + g * 4);
#pragma unroll
    for (int c = 0; c < 4; c++) sa[c] = *(const i32x4*)(srcS + c * 8);
    __syncthreads();   // z_lds init + s_plus staged

    for (int kk = 0; kk < ksteps; kk++) {
        const int k0 = kk * 64;
        // exp + stage E tile from regs
        {
            float zp = 0.f;
            unsigned short* ep = e_lds + eh * 72 + ei;
#pragma unroll
            for (int g = 0; g < 4; g++) {
                int i0 = k0 + ei + g * 4;
                float e0 = (i0 + 0 < n) ? __expf(ea[g].x) : 0.f;
                float e1 = (i0 + 1 < n) ? __expf(ea[g].y) : 0.f;
                float e2 = (i0 + 2 < n) ? __expf(ea[g].z) : 0.f;
                float e3 = (i0 + 3 < n) ? __expf(ea[g].w) : 0.f;
                zp += (e0 + e1) + (e2 + e3);
                int2 o; o.x = pack2(f2bf(e0), f2bf(e1)); o.y = pack2(f2bf(e2), f2bf(e3));
                *(int2*)(ep + g * 4) = o;
            }
            zp += __shfl_xor(zp, 1);
            zp += __shfl_xor(zp, 2);
            if ((t & 3) == 0) z_lds[eh] += zp;
        }
        // stage S tile from regs (threads t and t+128 share row t&127)
        {
            unsigned short* dp = s_lds + srow * 72 + skh;
#pragma unroll
            for (int c = 0; c < 4; c++) *(i32x4*)(dp + c * 8) = sa[c];
        }
        __syncthreads();
        // prefetch k+1 (in flight during MFMA phase)
        if (kk + 1 < ksteps) {
#pragma unroll
            for (int g = 0; g < 4; g++) ea[g] = *(const f32x4*)(arow + k0 + 64 + g * 4);
#pragma unroll
            for (int c = 0; c < 4; c++) sa[c] = *(const i32x4*)(srcS + k0 + 64 + c * 8);
        }
        // MFMA: D[b][h] += S[b,i] * E[h,i] ; wave owns 32 b rows
        {
            const unsigned short* sA  = s_lds + (wv * 32 + r) * 72;
            const unsigned short* sB0 = e_lds + r * 72;
            const unsigned short* sB1 = sB0 + 32 * 72;
#pragma unroll
            for (int kq = 0; kq < 4; kq++) {
                const int ko = kq * 16 + half * 8;
                bf16x8 A0 = *(const bf16x8*)(sA + ko);
                bf16x8 B0 = *(const bf16x8*)(sB0 + ko);
                bf16x8 B1 = *(const bf16x8*)(sB1 + ko);
                acc0 = __builtin_amdgcn_mfma_f32_32x32x16_bf16(A0, B0, acc0, 0, 0, 0);
                acc1 = __builtin_amdgcn_mfma_f32_32x32x16_bf16(A0, B1, acc1, 0, 0, 0);
            }
        }
        __syncthreads();
    }
    // epilogue: scale by 1/Z[h], write q tile (b rows, stride 72) into s_lds.
    // Each wave writes ONLY its own 32 rows -> no barrier needed before phase 2.
    {
        float rz0 = 1.0f / z_lds[r];
        float rz1 = 1.0f / z_lds[32 + r];
#pragma unroll
        for (int reg = 0; reg < 16; reg++) {
            int row = (reg & 3) + 8 * (reg >> 2) + 4 * half;
            s_lds[(wv * 32 + row) * 72 + r]      = f2bf(acc0[reg] * rz0);
            s_lds[(wv * 32 + row) * 72 + 32 + r] = f2bf(acc1[reg] * rz1);
        }
    }

    // ================= phase 2: retrieval softmax (wave owns 32 b) ==========
    bf16x8 p[4];
#pragma unroll
    for (int kq = 0; kq < 4; kq++)
        p[kq] = *(const bf16x8*)(phimu + r * NH + kq * 16 + half * 8);
    bf16x8 q[4];
#pragma unroll
    for (int kq = 0; kq < 4; kq++)
        q[kq] = *(const bf16x8*)(s_lds + (wv * 32 + r) * 72 + kq * 16 + half * 8);

    f32x4 den = {0.f,0.f,0.f,0.f}, num = {0.f,0.f,0.f,0.f};

    for (int it = 0; it < 32; ++it) {
        bf16x8 pn[4];
        if (it < 31) {   // prefetch next m-tile (no barrier in loop: stays in flight)
#pragma unroll
            for (int kq = 0; kq < 4; kq++)
                pn[kq] = *(const bf16x8*)(phimu + ((it + 1) * 32 + r) * NH + kq * 16 + half * 8);
        }
        f32x16 a0;
#pragma unroll
        for (int i = 0; i < 16; i++) a0[i] = 0.f;
#pragma unroll
        for (int kq = 0; kq < 4; kq++)
            a0 = __builtin_amdgcn_mfma_f32_32x32x16_bf16(p[kq], q[kq], a0, 0, 0, 0);
        const int mb = it * 32;
#pragma unroll
        for (int g = 0; g < 4; g++) {
            f32x4 pv = *(const f32x4*)(s_plus + mb + 4 * half + 8 * g);
            f32x4 e;
#pragma unroll
            for (int j = 0; j < 4; j++) e[j] = EXP2F(a0[4 * g + j]);   // m = mb + j + 8*g + 4*half
            den += e; num += e * pv;
        }
        if (it < 31) {
#pragma unroll
            for (int kq = 0; kq < 4; kq++) p[kq] = pn[kq];
        }
    }
    float d  = (den[0] + den[1]) + (den[2] + den[3]);
    float nu = (num[0] + num[1]) + (num[2] + num[3]);
    // combine the two m-halves (same b, complementary m rows)
    d += __shfl_xor(d, 32); nu += __shfl_xor(nu, 32);

    // per-b results: wave wv owns b_local = wv*32 + r (all m done inside wave)
    float* dsum = (float*)e_lds;          // 128 floats (e_lds dead after phase 1)
    float* nsum = dsum + 128;
    if (half == 0) { dsum[wv * 32 + r] = d; nsum[wv * 32 + r] = nu; }
    __syncthreads();
    // BCE for b_local = t (t < 128)
    float bce = 0.f;
    if (t < 128) {
        float dd = dsum[t], nn2 = nsum[t];
        float p2 = nn2 / dd;
        p2 = fminf(fmaxf(p2, 1e-6f), 1.0f - 1e-6f);
        float tg = seq[(size_t)(boff + t) * NPOS + n];
        bce = (tg > 0.f) ? -logf(p2) : -logf(1.0f - p2);
    }
#pragma unroll
    for (int o = 32; o; o >>= 1) bce += __shfl_xor(bce, o);
    if (lane == 0) z_lds[wv] = bce;       // z_lds reusable (rz consumed in epilogue)
    __syncthreads();
    if (t == 0)
        atomicAdd(out, (z_lds[0] + z_lds[1] + z_lds[2] + z_lds[3]) * (1.0f / 130816.0f));
}

extern "C" void kernel_launch(void* const* d_in, const int* in_sizes, int n_in,
                              void* d_out, int out_size, void* d_ws, size_t ws_size,
                              hipStream_t stream) {
    const float* seq = (const float*)d_in[0];  // (B,N)
    const float* mem = (const float*)d_in[1];  // (M,N)
    const float* Al  = (const float*)d_in[2];  // (N,H,N)
    const float* Bl  = (const float*)d_in[3];  // (H,N)

    char* ws = (char*)d_ws;
    unsigned short* seq_bf = (unsigned short*)(ws + 0);          // 256 KB
    float*          BnT    = (float*)(ws + 262144);              // 128 KB (N,H)
    unsigned short* phimu  = (unsigned short*)(ws + 393216);     // 128 KB (M,H) *log2e
    float*          plusT  = (float*)(ws + 524288);              // 2 MB (N,M)
    float*          outp   = (float*)d_out;

    kA_prep<<<272, 256, 0, stream>>>(seq, Bl, mem, seq_bf, BnT, plusT, outp);
    k1b_phimu<<<512, 256, 0, stream>>>(BnT, mem, phimu);
    k23_fused<<<1022, 256, 0, stream>>>(Al, seq_bf, phimu, plusT, seq, outp);
}

// Round 2
// 173.694 us; speedup vs baseline: 1.0334x; 1.0334x over previous
//
#include <hip/hip_runtime.h>
#include <stdint.h>

// Problem constants (fixed by reference setup_inputs)
#define NPOS 512   // N
#define NH   64    // H
#define NM   1024  // M
#define NB   256   // B
#define NM1  511   // N-1

typedef __attribute__((ext_vector_type(8)))  short bf16x8;
typedef __attribute__((ext_vector_type(16))) float f32x16;
typedef __attribute__((ext_vector_type(4)))  float f32x4;
typedef __attribute__((ext_vector_type(4)))  int   i32x4;

#if __has_builtin(__builtin_amdgcn_exp2f)
#define EXP2F(x) __builtin_amdgcn_exp2f(x)
#else
#define EXP2F(x) __expf((x) * 0.69314718055994531f)
#endif

__device__ __forceinline__ unsigned short f2bf(float x) {
    unsigned u = __float_as_uint(x);
    u = (u + 0x7FFFu + ((u >> 16) & 1u)) >> 16;   // RNE
    return (unsigned short)u;
}
__device__ __forceinline__ int pack2(unsigned short a, unsigned short b) {
    return (int)a | ((int)b << 16);
}

// ---------------- kA: fused prep = {k0 seq->bf16 + zero out, k1a BnT softmax,
//                  k1c plusT transpose}. 272 blocks x 256 thr. ----------------
__global__ __launch_bounds__(256, 4)
void kA_prep(const float* __restrict__ seq, const float* __restrict__ Bl,
             const float* __restrict__ mem,
             unsigned short* __restrict__ seq_bf, float* __restrict__ BnT,
             float* __restrict__ plusT, float* __restrict__ out) {
    const int bid = blockIdx.x, t = threadIdx.x;
    if (bid < 128) {
        // --- k0: sequences fp32 -> bf16 (exact for +/-1) ---
        if (bid == 0 && t == 0) out[0] = 0.f;
        int idx = (bid * 256 + t) * 4;
        f32x4 v = *(const f32x4*)(seq + idx);
        int2 o;
        o.x = pack2(f2bf(v.x), f2bf(v.y));
        o.y = pack2(f2bf(v.z), f2bf(v.w));
        *(int2*)(seq_bf + idx) = o;
    } else if (bid < 144) {
        // --- k1a: Bn = softmax(B_logits, axis=-1), stored transposed ---
        const int h = (bid - 128) * 4 + (t >> 6), l = t & 63;
        float v[8]; float mx = -1e30f;
#pragma unroll
        for (int j = 0; j < 8; j++) { v[j] = Bl[h * NPOS + l + 64 * j]; mx = fmaxf(mx, v[j]); }
#pragma unroll
        for (int o = 32; o; o >>= 1) mx = fmaxf(mx, __shfl_xor(mx, o));
        float s = 0.f;
#pragma unroll
        for (int j = 0; j < 8; j++) { v[j] = __expf(v[j] - mx); s += v[j]; }
#pragma unroll
        for (int o = 32; o; o >>= 1) s += __shfl_xor(s, o);
        float r = 1.0f / s;
#pragma unroll
        for (int j = 0; j < 8; j++) BnT[(l + 64 * j) * NH + h] = v[j] * r;
    } else {
        // --- k1c: plusT[n][m] via LDS 64x64 tile transpose ---
        __shared__ float sT[64][65];
        const int bb = bid - 144;
        const int mt = bb >> 3, nt = bb & 7;
        const int rr = t >> 2, cc = t & 3;
        const float* src = mem + (size_t)(mt * 64 + rr) * NPOS + nt * 64 + cc * 16;
#pragma unroll
        for (int j = 0; j < 4; j++) {
            f32x4 v = *(const f32x4*)(src + j * 4);
            sT[rr][cc * 16 + j * 4 + 0] = (v.x > 0.f) ? 1.f : 0.f;
            sT[rr][cc * 16 + j * 4 + 1] = (v.y > 0.f) ? 1.f : 0.f;
            sT[rr][cc * 16 + j * 4 + 2] = (v.z > 0.f) ? 1.f : 0.f;
            sT[rr][cc * 16 + j * 4 + 3] = (v.w > 0.f) ? 1.f : 0.f;
        }
        __syncthreads();
        float* dst = plusT + (size_t)(nt * 64 + rr) * NM + mt * 64 + cc * 16;
#pragma unroll
        for (int j = 0; j < 4; j++) {
            f32x4 o;
            o.x = sT[cc * 16 + j * 4 + 0][rr];
            o.y = sT[cc * 16 + j * 4 + 1][rr];
            o.z = sT[cc * 16 + j * 4 + 2][rr];
            o.w = sT[cc * 16 + j * 4 + 3][rr];
            *(f32x4*)(dst + j * 4) = o;
        }
    }
}

// ---------------- k1b: phi_mu[m,h] = sum_n Bn[h,n]*memory[m,n] -> bf16 -------
// 512 blocks x 2 m-rows, 4 independent fma chains. PRE-SCALED by log2(e).
__global__ __launch_bounds__(256, 4)
void k1b_phimu(const float* __restrict__ BnT, const float* __restrict__ mem,
               unsigned short* __restrict__ phimu) {
    const int m0 = blockIdx.x * 2, t = threadIdx.x;
    __shared__ float mrow[2][NPOS];
    __shared__ float part[2][256];
    {
        int row = t >> 7, c = (t & 127) * 4;
        *(f32x4*)(&mrow[row][c]) = *(const f32x4*)(mem + (size_t)(m0 + row) * NPOS + c);
    }
    __syncthreads();
    const int h = t & 63, seg = t >> 6;
    float a[2] = {0.f, 0.f};
    float b2[2] = {0.f, 0.f};
    const float* bp = BnT + seg * 128 * NH + h;
#pragma unroll 8
    for (int nn = 0; nn < 128; nn += 2) {
        float x0 = bp[nn * NH], x1 = bp[(nn + 1) * NH];
#pragma unroll
        for (int row = 0; row < 2; row++) {
            a[row]  = fmaf(x0, mrow[row][seg * 128 + nn], a[row]);
            b2[row] = fmaf(x1, mrow[row][seg * 128 + nn + 1], b2[row]);
        }
    }
#pragma unroll
    for (int row = 0; row < 2; row++) part[row][t] = a[row] + b2[row];
    __syncthreads();
    if (t < 64) {
#pragma unroll
        for (int row = 0; row < 2; row++) {
            float s = (part[row][t] + part[row][t + 64]) + (part[row][t + 128] + part[row][t + 192]);
            phimu[(m0 + row) * NH + t] = f2bf(s * 1.4426950408889634f);  // * log2(e)
        }
    }
}

// ---------------- k23: FUSED hat_phi + retrieval softmax + BCE ---------------
// grid 511 (one block per n — NO duplicated per-n work), 512 thr = 8 waves.
// LDS ~50 KB -> 2 blocks/CU = 16 waves/CU = 4 waves/SIMD (2x round-0), with
// per-thread staging cost halved (8 exps/k-step, half an S-row).
// Phase 1: masked-softmax(A_logits[n]) GEMM seq -> hat_phi 256b x 64h in LDS;
//          wave wv owns 32 b rows (acc0: h 0-31, acc1: h 32-63).
// Phase 2: wave wv owns the same 32 b; 32 m-tiles of 32, p prefetched 1 ahead,
//          exp2 streaming softmax (phimu pre-scaled by log2e), BCE epilogue.
__global__ __launch_bounds__(512, 4)
void k23_fused(const float* __restrict__ Al, const unsigned short* __restrict__ seq_bf,
               const unsigned short* __restrict__ phimu, const float* __restrict__ plusT,
               const float* __restrict__ seq, float* __restrict__ out) {
    __shared__ __align__(16) unsigned short s_lds[256 * 72];  // S tile -> q tile (36864 B)
    __shared__ __align__(16) unsigned short e_lds[64 * 72];   // E tile -> dsum/nsum (9216 B)
    __shared__ float z_lds[64];                               // row sums Z[h] -> wave partials
    __shared__ float s_plus[NM];

    const int t = threadIdx.x;
    const int n = NM1 - (int)blockIdx.x;          // n in 1..511, big n first
    const int ksteps = (n + 63) >> 6;
    const int wv = t >> 6, lane = t & 63, half = lane >> 5, r = lane & 31;

    if (t < 64) z_lds[t] = 0.f;
    // stage plus row early (independent of phase 1)
    if (t < 256) *(f32x4*)(s_plus + t * 4) = *(const f32x4*)(plusT + (size_t)n * NM + t * 4);

    // ================= phase 1: hat_phi tile (256 b x 64 h) =================
    // E staging: 8 threads per h row, 8 elements each.
    const int eh = t >> 3, ei = (t & 7) * 8;
    const float* arow = Al + ((size_t)n * NH + eh) * NPOS + ei;
    // S staging: threads t and t+256 stage the two 32-wide halves of row t&255.
    const int srow = t & 255, skh = (t >> 8) * 32;
    const unsigned short* srcS = seq_bf + (size_t)srow * NPOS + skh;

    f32x16 acc0, acc1;
#pragma unroll
    for (int i = 0; i < 16; i++) { acc0[i] = 0.f; acc1[i] = 0.f; }

    f32x4 ea[2]; i32x4 sa[4];
#pragma unroll
    for (int g = 0; g < 2; g++) ea[g] = *(const f32x4*)(arow + g * 4);
#pragma unroll
    for (int c = 0; c < 4; c++) sa[c] = *(const i32x4*)(srcS + c * 8);
    __syncthreads();   // z_lds init + s_plus staged

    for (int kk = 0; kk < ksteps; kk++) {
        const int k0 = kk * 64;
        // exp + stage E tile from regs
        {
            float zp = 0.f;
            unsigned short* ep = e_lds + eh * 72 + ei;
#pragma unroll
            for (int g = 0; g < 2; g++) {
                int i0 = k0 + ei + g * 4;
                float e0 = (i0 + 0 < n) ? __expf(ea[g].x) : 0.f;
                float e1 = (i0 + 1 < n) ? __expf(ea[g].y) : 0.f;
                float e2 = (i0 + 2 < n) ? __expf(ea[g].z) : 0.f;
                float e3 = (i0 + 3 < n) ? __expf(ea[g].w) : 0.f;
                zp += (e0 + e1) + (e2 + e3);
                int2 o; o.x = pack2(f2bf(e0), f2bf(e1)); o.y = pack2(f2bf(e2), f2bf(e3));
                *(int2*)(ep + g * 4) = o;
            }
            zp += __shfl_xor(zp, 1);
            zp += __shfl_xor(zp, 2);
            zp += __shfl_xor(zp, 4);
            if ((t & 7) == 0) z_lds[eh] += zp;
        }
        // stage S tile from regs
        {
            unsigned short* dp = s_lds + srow * 72 + skh;
#pragma unroll
            for (int c = 0; c < 4; c++) *(i32x4*)(dp + c * 8) = sa[c];
        }
        __syncthreads();
        // prefetch k+1 (in flight during MFMA phase)
        if (kk + 1 < ksteps) {
#pragma unroll
            for (int g = 0; g < 2; g++) ea[g] = *(const f32x4*)(arow + k0 + 64 + g * 4);
#pragma unroll
            for (int c = 0; c < 4; c++) sa[c] = *(const i32x4*)(srcS + k0 + 64 + c * 8);
        }
        // MFMA: D[b][h] += S[b,i] * E[h,i] ; wave owns 32 b rows
        {
            const unsigned short* sA  = s_lds + (wv * 32 + r) * 72;
            const unsigned short* sB0 = e_lds + r * 72;
            const unsigned short* sB1 = sB0 + 32 * 72;
#pragma unroll
            for (int kq = 0; kq < 4; kq++) {
                const int ko = kq * 16 + half * 8;
                bf16x8 A0 = *(const bf16x8*)(sA + ko);
                bf16x8 B0 = *(const bf16x8*)(sB0 + ko);
                bf16x8 B1 = *(const bf16x8*)(sB1 + ko);
                acc0 = __builtin_amdgcn_mfma_f32_32x32x16_bf16(A0, B0, acc0, 0, 0, 0);
                acc1 = __builtin_amdgcn_mfma_f32_32x32x16_bf16(A0, B1, acc1, 0, 0, 0);
            }
        }
        __syncthreads();
    }
    // epilogue: scale by 1/Z[h], write q tile (b rows, stride 72) into s_lds.
    // Each wave writes ONLY its own 32 rows -> no barrier needed before phase 2.
    {
        float rz0 = 1.0f / z_lds[r];
        float rz1 = 1.0f / z_lds[32 + r];
#pragma unroll
        for (int reg = 0; reg < 16; reg++) {
            int row = (reg & 3) + 8 * (reg >> 2) + 4 * half;
            s_lds[(wv * 32 + row) * 72 + r]      = f2bf(acc0[reg] * rz0);
            s_lds[(wv * 32 + row) * 72 + 32 + r] = f2bf(acc1[reg] * rz1);
        }
    }

    // ================= phase 2: retrieval softmax (wave owns 32 b) ==========
    bf16x8 p[4];
#pragma unroll
    for (int kq = 0; kq < 4; kq++)
        p[kq] = *(const bf16x8*)(phimu + r * NH + kq * 16 + half * 8);
    bf16x8 q[4];
#pragma unroll
    for (int kq = 0; kq < 4; kq++)
        q[kq] = *(const bf16x8*)(s_lds + (wv * 32 + r) * 72 + kq * 16 + half * 8);

    f32x4 den = {0.f,0.f,0.f,0.f}, num = {0.f,0.f,0.f,0.f};

    for (int it = 0; it < 32; ++it) {
        bf16x8 pn[4];
        if (it < 31) {   // prefetch next m-tile (no barrier in loop: stays in flight)
#pragma unroll
            for (int kq = 0; kq < 4; kq++)
                pn[kq] = *(const bf16x8*)(phimu + ((it + 1) * 32 + r) * NH + kq * 16 + half * 8);
        }
        f32x16 a0;
#pragma unroll
        for (int i = 0; i < 16; i++) a0[i] = 0.f;
#pragma unroll
        for (int kq = 0; kq < 4; kq++)
            a0 = __builtin_amdgcn_mfma_f32_32x32x16_bf16(p[kq], q[kq], a0, 0, 0, 0);
        const int mb = it * 32;
#pragma unroll
        for (int g = 0; g < 4; g++) {
            f32x4 pv = *(const f32x4*)(s_plus + mb + 4 * half + 8 * g);
            f32x4 e;
#pragma unroll
            for (int j = 0; j < 4; j++) e[j] = EXP2F(a0[4 * g + j]);   // m = mb + j + 8*g + 4*half
            den += e; num += e * pv;
        }
        if (it < 31) {
#pragma unroll
            for (int kq = 0; kq < 4; kq++) p[kq] = pn[kq];
        }
    }
    float d  = (den[0] + den[1]) + (den[2] + den[3]);
    float nu = (num[0] + num[1]) + (num[2] + num[3]);
    // combine the two m-halves (same b, complementary m rows)
    d += __shfl_xor(d, 32); nu += __shfl_xor(nu, 32);

    // per-b results: wave wv owns b = wv*32 + r (all m done inside wave)
    float* dsum = (float*)e_lds;          // 256 floats (e_lds dead after phase 1)
    float* nsum = dsum + 256;
    if (half == 0) { dsum[wv * 32 + r] = d; nsum[wv * 32 + r] = nu; }
    __syncthreads();
    // BCE for b = t (t < 256)
    float bce = 0.f;
    if (t < 256) {
        float dd = dsum[t], nn2 = nsum[t];
        float p2 = nn2 / dd;
        p2 = fminf(fmaxf(p2, 1e-6f), 1.0f - 1e-6f);
        float tg = seq[(size_t)t * NPOS + n];
        bce = (tg > 0.f) ? -logf(p2) : -logf(1.0f - p2);
    }
#pragma unroll
    for (int o = 32; o; o >>= 1) bce += __shfl_xor(bce, o);
    if (lane == 0) z_lds[wv] = bce;       // z_lds reusable (rz consumed in epilogue)
    __syncthreads();
    if (t == 0) {
        float s = ((z_lds[0] + z_lds[1]) + (z_lds[2] + z_lds[3]))
                + ((z_lds[4] + z_lds[5]) + (z_lds[6] + z_lds[7]));
        atomicAdd(out, s * (1.0f / 130816.0f));
    }
}

extern "C" void kernel_launch(void* const* d_in, const int* in_sizes, int n_in,
                              void* d_out, int out_size, void* d_ws, size_t ws_size,
                              hipStream_t stream) {
    const float* seq = (const float*)d_in[0];  // (B,N)
    const float* mem = (const float*)d_in[1];  // (M,N)
    const float* Al  = (const float*)d_in[2];  // (N,H,N)
    const float* Bl  = (const float*)d_in[3];  // (H,N)

    char* ws = (char*)d_ws;
    unsigned short* seq_bf = (unsigned short*)(ws + 0);          // 256 KB
    float*          BnT    = (float*)(ws + 262144);              // 128 KB (N,H)
    unsigned short* phimu  = (unsigned short*)(ws + 393216);     // 128 KB (M,H) *log2e
    float*          plusT  = (float*)(ws + 524288);              // 2 MB (N,M)
    float*          outp   = (float*)d_out;

    kA_prep<<<272, 256, 0, stream>>>(seq, Bl, mem, seq_bf, BnT, plusT, outp);
    k1b_phimu<<<512, 256, 0, stream>>>(BnT, mem, phimu);
    k23_fused<<<511, 512, 0, stream>>>(Al, seq_bf, phimu, plusT, seq, outp);
}

// Round 3
// 148.376 us; speedup vs baseline: 1.2098x; 1.1706x over previous
//
#include <hip/hip_runtime.h>
#include <stdint.h>

// Problem constants (fixed by reference setup_inputs)
#define NPOS 512   // N
#define NH   64    // H
#define NM   1024  // M
#define NB   256   // B
#define NM1  511   // N-1

typedef __attribute__((ext_vector_type(8)))  short bf16x8;
typedef __attribute__((ext_vector_type(16))) float f32x16;
typedef __attribute__((ext_vector_type(4)))  float f32x4;
typedef __attribute__((ext_vector_type(4)))  int   i32x4;

#if __has_builtin(__builtin_amdgcn_exp2f)
#define EXP2F(x) __builtin_amdgcn_exp2f(x)
#else
#define EXP2F(x) __expf((x) * 0.69314718055994531f)
#endif

__device__ __forceinline__ unsigned short f2bf(float x) {
    unsigned u = __float_as_uint(x);
    u = (u + 0x7FFFu + ((u >> 16) & 1u)) >> 16;   // RNE
    return (unsigned short)u;
}
__device__ __forceinline__ int pack2(unsigned short a, unsigned short b) {
    return (int)a | ((int)b << 16);
}

// ---------------- kA: fused prep = {k0 seq->bf16 + zero out, k1a BnT softmax,
//                  k1c plusT transpose}. 272 blocks x 256 thr. ----------------
__global__ __launch_bounds__(256, 4)
void kA_prep(const float* __restrict__ seq, const float* __restrict__ Bl,
             const float* __restrict__ mem,
             unsigned short* __restrict__ seq_bf, float* __restrict__ BnT,
             float* __restrict__ plusT, float* __restrict__ out) {
    const int bid = blockIdx.x, t = threadIdx.x;
    if (bid < 128) {
        // --- k0: sequences fp32 -> bf16 (exact for +/-1) ---
        if (bid == 0 && t == 0) out[0] = 0.f;
        int idx = (bid * 256 + t) * 4;
        f32x4 v = *(const f32x4*)(seq + idx);
        int2 o;
        o.x = pack2(f2bf(v.x), f2bf(v.y));
        o.y = pack2(f2bf(v.z), f2bf(v.w));
        *(int2*)(seq_bf + idx) = o;
    } else if (bid < 144) {
        // --- k1a: Bn = softmax(B_logits, axis=-1), stored transposed ---
        const int h = (bid - 128) * 4 + (t >> 6), l = t & 63;
        float v[8]; float mx = -1e30f;
#pragma unroll
        for (int j = 0; j < 8; j++) { v[j] = Bl[h * NPOS + l + 64 * j]; mx = fmaxf(mx, v[j]); }
#pragma unroll
        for (int o = 32; o; o >>= 1) mx = fmaxf(mx, __shfl_xor(mx, o));
        float s = 0.f;
#pragma unroll
        for (int j = 0; j < 8; j++) { v[j] = __expf(v[j] - mx); s += v[j]; }
#pragma unroll
        for (int o = 32; o; o >>= 1) s += __shfl_xor(s, o);
        float r = 1.0f / s;
#pragma unroll
        for (int j = 0; j < 8; j++) BnT[(l + 64 * j) * NH + h] = v[j] * r;
    } else {
        // --- k1c: plusT[n][m] via LDS 64x64 tile transpose ---
        __shared__ float sT[64][65];
        const int bb = bid - 144;
        const int mt = bb >> 3, nt = bb & 7;
        const int rr = t >> 2, cc = t & 3;
        const float* src = mem + (size_t)(mt * 64 + rr) * NPOS + nt * 64 + cc * 16;
#pragma unroll
        for (int j = 0; j < 4; j++) {
            f32x4 v = *(const f32x4*)(src + j * 4);
            sT[rr][cc * 16 + j * 4 + 0] = (v.x > 0.f) ? 1.f : 0.f;
            sT[rr][cc * 16 + j * 4 + 1] = (v.y > 0.f) ? 1.f : 0.f;
            sT[rr][cc * 16 + j * 4 + 2] = (v.z > 0.f) ? 1.f : 0.f;
            sT[rr][cc * 16 + j * 4 + 3] = (v.w > 0.f) ? 1.f : 0.f;
        }
        __syncthreads();
        float* dst = plusT + (size_t)(nt * 64 + rr) * NM + mt * 64 + cc * 16;
#pragma unroll
        for (int j = 0; j < 4; j++) {
            f32x4 o;
            o.x = sT[cc * 16 + j * 4 + 0][rr];
            o.y = sT[cc * 16 + j * 4 + 1][rr];
            o.z = sT[cc * 16 + j * 4 + 2][rr];
            o.w = sT[cc * 16 + j * 4 + 3][rr];
            *(f32x4*)(dst + j * 4) = o;
        }
    }
}

// ---------------- k1b: phi_mu[m,h] = sum_n Bn[h,n]*memory[m,n] -> bf16 -------
// 512 blocks x 2 m-rows, 4 independent fma chains. PRE-SCALED by log2(e).
__global__ __launch_bounds__(256, 4)
void k1b_phimu(const float* __restrict__ BnT, const float* __restrict__ mem,
               unsigned short* __restrict__ phimu) {
    const int m0 = blockIdx.x * 2, t = threadIdx.x;
    __shared__ float mrow[2][NPOS];
    __shared__ float part[2][256];
    {
        int row = t >> 7, c = (t & 127) * 4;
        *(f32x4*)(&mrow[row][c]) = *(const f32x4*)(mem + (size_t)(m0 + row) * NPOS + c);
    }
    __syncthreads();
    const int h = t & 63, seg = t >> 6;
    float a[2] = {0.f, 0.f};
    float b2[2] = {0.f, 0.f};
    const float* bp = BnT + seg * 128 * NH + h;
#pragma unroll 8
    for (int nn = 0; nn < 128; nn += 2) {
        float x0 = bp[nn * NH], x1 = bp[(nn + 1) * NH];
#pragma unroll
        for (int row = 0; row < 2; row++) {
            a[row]  = fmaf(x0, mrow[row][seg * 128 + nn], a[row]);
            b2[row] = fmaf(x1, mrow[row][seg * 128 + nn + 1], b2[row]);
        }
    }
#pragma unroll
    for (int row = 0; row < 2; row++) part[row][t] = a[row] + b2[row];
    __syncthreads();
    if (t < 64) {
#pragma unroll
        for (int row = 0; row < 2; row++) {
            float s = (part[row][t] + part[row][t + 64]) + (part[row][t + 128] + part[row][t + 192]);
            phimu[(m0 + row) * NH + t] = f2bf(s * 1.4426950408889634f);  // * log2(e)
        }
    }
}

// ------------- phase-2 helpers (static indexing only; rule #20) --------------
__device__ __forceinline__ void p2_load(bf16x8 (&p)[4], const unsigned short* __restrict__ phimu,
                                        int tile, int r, int half) {
#pragma unroll
    for (int kq = 0; kq < 4; kq++)
        p[kq] = *(const bf16x8*)(phimu + (size_t)(tile * 32 + r) * NH + kq * 16 + half * 8);
}
__device__ __forceinline__ void p2_mfma(const bf16x8 (&p)[4], const bf16x8 (&q0)[4], const bf16x8 (&q1)[4],
                                        f32x16& a0, f32x16& a1) {
#pragma unroll
    for (int i = 0; i < 16; i++) { a0[i] = 0.f; a1[i] = 0.f; }
#pragma unroll
    for (int kq = 0; kq < 4; kq++) {
        a0 = __builtin_amdgcn_mfma_f32_32x32x16_bf16(p[kq], q0[kq], a0, 0, 0, 0);
        a1 = __builtin_amdgcn_mfma_f32_32x32x16_bf16(p[kq], q1[kq], a1, 0, 0, 0);
    }
}
__device__ __forceinline__ void p2_expsum(const f32x16& a0, const f32x16& a1, const float* s_plus,
                                          int mb, int half,
                                          f32x4& den0, f32x4& num0, f32x4& den1, f32x4& num1) {
#pragma unroll
    for (int g = 0; g < 4; g++) {
        f32x4 pv = *(const f32x4*)(s_plus + mb + 4 * half + 8 * g);
        f32x4 e0, e1;
#pragma unroll
        for (int j = 0; j < 4; j++) {
            e0[j] = EXP2F(a0[4 * g + j]);   // m = mb + j + 8*g + 4*half
            e1[j] = EXP2F(a1[4 * g + j]);
        }
        den0 += e0; num0 += e0 * pv;
        den1 += e1; num1 += e1 * pv;
    }
}

// ---------------- k23: FUSED hat_phi + retrieval softmax + BCE ---------------
// grid 511 (one block per n), 256 thr = 4 waves. Round-0 base (best measured)
// with critical-path fixes:
//  * Phase 1: S-fragments read DIRECTLY from global (L2-resident; same scatter
//    as the old staging loads) -> no S LDS roundtrip. E double-buffered ->
//    ONE raw s_barrier per k-step (lgkmcnt(0) only); A/S prefetches stay in
//    flight ACROSS the barrier (no vmcnt drain).
//  * Phase 2: 2-tile software pipeline: MFMA(tile it+1) + p-loads(it+2/it+3)
//    overlap the 32-exp VALU block of tile it.
__global__ __launch_bounds__(256, 2)
void k23_fused(const float* __restrict__ Al, const unsigned short* __restrict__ seq_bf,
               const unsigned short* __restrict__ phimu, const float* __restrict__ plusT,
               const float* __restrict__ seq, float* __restrict__ out) {
    __shared__ __align__(16) unsigned short e_lds[2][64 * 72];   // E double buffer (2x9216 B)
    __shared__ __align__(16) unsigned short q_lds[256 * 72];     // q tile (36864 B)
    __shared__ float z_lds[64];                                  // row sums Z[h] -> wave partials
    __shared__ float s_plus[NM];

    const int t = threadIdx.x;
    const int n = NM1 - (int)blockIdx.x;          // n in 1..511, big n first
    const int ksteps = (n + 63) >> 6;
    const int wv = t >> 6, lane = t & 63, half = lane >> 5, r = lane & 31;

    if (t < 64) z_lds[t] = 0.f;
    // stage plus row early (independent of phase 1)
    *(f32x4*)(s_plus + t * 4) = *(const f32x4*)(plusT + (size_t)n * NM + t * 4);

    // ================= phase 1: hat_phi tile (256 b x 64 h) =================
    const int eh = t >> 2, ei = (t & 3) * 16;
    const float* arow = Al + ((size_t)n * NH + eh) * NPOS + ei;
    // S-fragment base rows for this lane (wave wv owns b rows wv*64..wv*64+63)
    const unsigned short* s0 = seq_bf + (size_t)(wv * 64 + r) * NPOS;        // bs=0
    const unsigned short* s1 = seq_bf + (size_t)(wv * 64 + 32 + r) * NPOS;   // bs=1

    f32x16 acc00, acc01, acc10, acc11;
#pragma unroll
    for (int i = 0; i < 16; i++) { acc00[i] = 0.f; acc01[i] = 0.f; acc10[i] = 0.f; acc11[i] = 0.f; }

    f32x4 ea[4];
    bf16x8 sc0[4], sc1[4], sn0[4], sn1[4];
#pragma unroll
    for (int g = 0; g < 4; g++) ea[g] = *(const f32x4*)(arow + g * 4);
#pragma unroll
    for (int kq = 0; kq < 4; kq++) {
        sc0[kq] = *(const bf16x8*)(s0 + kq * 16 + half * 8);
        sc1[kq] = *(const bf16x8*)(s1 + kq * 16 + half * 8);
    }
    __syncthreads();   // z_lds init + s_plus staged (once; full barrier is fine here)

    for (int kk = 0; kk < ksteps; kk++) {
        const int k0 = kk * 64;
        unsigned short* ebuf = e_lds[kk & 1];
        // 1. exp + stage E tile from regs (masked), accumulate Z
        {
            float zp = 0.f;
            unsigned short* ep = ebuf + eh * 72 + ei;
#pragma unroll
            for (int g = 0; g < 4; g++) {
                int i0 = k0 + ei + g * 4;
                float e0 = (i0 + 0 < n) ? __expf(ea[g].x) : 0.f;
                float e1 = (i0 + 1 < n) ? __expf(ea[g].y) : 0.f;
                float e2 = (i0 + 2 < n) ? __expf(ea[g].z) : 0.f;
                float e3 = (i0 + 3 < n) ? __expf(ea[g].w) : 0.f;
                zp += (e0 + e1) + (e2 + e3);
                int2 o; o.x = pack2(f2bf(e0), f2bf(e1)); o.y = pack2(f2bf(e2), f2bf(e3));
                *(int2*)(ep + g * 4) = o;
            }
            zp += __shfl_xor(zp, 1);
            zp += __shfl_xor(zp, 2);
            if ((t & 3) == 0) z_lds[eh] += zp;
        }
        // 2. prefetch k+1 (A row + S fragments) — stays in flight across the barrier
        if (kk + 1 < ksteps) {
#pragma unroll
            for (int g = 0; g < 4; g++) ea[g] = *(const f32x4*)(arow + k0 + 64 + g * 4);
#pragma unroll
            for (int kq = 0; kq < 4; kq++) {
                sn0[kq] = *(const bf16x8*)(s0 + k0 + 64 + kq * 16 + half * 8);
                sn1[kq] = *(const bf16x8*)(s1 + k0 + 64 + kq * 16 + half * 8);
            }
        }
        // 3. LDS-only fence + raw barrier (global prefetches NOT drained)
        asm volatile("s_waitcnt lgkmcnt(0)" ::: "memory");
        __builtin_amdgcn_s_barrier();
        asm volatile("" ::: "memory");
        // 4. MFMA: D[b][h] += S[b,i] * E[h,i] (A-frags from regs, B-frags from LDS)
        {
            const unsigned short* sB0 = ebuf + r * 72;
            const unsigned short* sB1 = sB0 + 32 * 72;
#pragma unroll
            for (int kq = 0; kq < 4; kq++) {
                const int ko = kq * 16 + half * 8;
                bf16x8 B0 = *(const bf16x8*)(sB0 + ko);
                bf16x8 B1 = *(const bf16x8*)(sB1 + ko);
                acc00 = __builtin_amdgcn_mfma_f32_32x32x16_bf16(sc0[kq], B0, acc00, 0, 0, 0);
                acc01 = __builtin_amdgcn_mfma_f32_32x32x16_bf16(sc0[kq], B1, acc01, 0, 0, 0);
                acc10 = __builtin_amdgcn_mfma_f32_32x32x16_bf16(sc1[kq], B0, acc10, 0, 0, 0);
                acc11 = __builtin_amdgcn_mfma_f32_32x32x16_bf16(sc1[kq], B1, acc11, 0, 0, 0);
            }
        }
        // 5. rotate S fragments
        if (kk + 1 < ksteps) {
#pragma unroll
            for (int kq = 0; kq < 4; kq++) { sc0[kq] = sn0[kq]; sc1[kq] = sn1[kq]; }
        }
    }
    // epilogue: scale by 1/Z[h], write q tile (b rows, stride 72) into q_lds.
    // Wave writes/reads ONLY its own 64 rows -> no barrier needed before phase 2.
    {
        float rz0 = 1.0f / z_lds[r];
        float rz1 = 1.0f / z_lds[32 + r];
#pragma unroll
        for (int reg = 0; reg < 16; reg++) {
            int row = (reg & 3) + 8 * (reg >> 2) + 4 * half;
            q_lds[(wv * 64 + row) * 72 + r]            = f2bf(acc00[reg] * rz0);
            q_lds[(wv * 64 + row) * 72 + 32 + r]       = f2bf(acc01[reg] * rz1);
            q_lds[(wv * 64 + 32 + row) * 72 + r]       = f2bf(acc10[reg] * rz0);
            q_lds[(wv * 64 + 32 + row) * 72 + 32 + r]  = f2bf(acc11[reg] * rz1);
        }
    }

    // ================= phase 2: retrieval softmax (pipelined) =================
    bf16x8 pA[4], pB[4];
    p2_load(pA, phimu, 0, r, half);            // global loads issue first
    p2_load(pB, phimu, 1, r, half);
    bf16x8 q0[4], q1[4];
#pragma unroll
    for (int kq = 0; kq < 4; kq++) {
        q0[kq] = *(const bf16x8*)(q_lds + (wv * 64 + r) * 72 + kq * 16 + half * 8);
        q1[kq] = *(const bf16x8*)(q_lds + (wv * 64 + 32 + r) * 72 + kq * 16 + half * 8);
    }

    f32x4 den0 = {0.f,0.f,0.f,0.f}, num0 = {0.f,0.f,0.f,0.f};
    f32x4 den1 = {0.f,0.f,0.f,0.f}, num1 = {0.f,0.f,0.f,0.f};
    f32x16 aA0, aA1, aB0, aB1;

    p2_mfma(pA, q0, q1, aA0, aA1);             // tile 0
    for (int it = 0; it < 32; it += 2) {
        if (it + 2 < 32) p2_load(pA, phimu, it + 2, r, half);   // issue early
        p2_mfma(pB, q0, q1, aB0, aB1);                          // tile it+1 (consumes pB)
        if (it + 3 < 32) p2_load(pB, phimu, it + 3, r, half);   // issue before VALU block
        p2_expsum(aA0, aA1, s_plus, it * 32, half, den0, num0, den1, num1);       // tile it
        if (it + 2 < 32) p2_mfma(pA, q0, q1, aA0, aA1);         // tile it+2
        p2_expsum(aB0, aB1, s_plus, (it + 1) * 32, half, den0, num0, den1, num1); // tile it+1
    }

    float d0 = (den0[0] + den0[1]) + (den0[2] + den0[3]);
    float nu0 = (num0[0] + num0[1]) + (num0[2] + num0[3]);
    float d1 = (den1[0] + den1[1]) + (den1[2] + den1[3]);
    float nu1 = (num1[0] + num1[1]) + (num1[2] + num1[3]);
    // combine the two m-halves (same b, complementary m rows)
    d0 += __shfl_xor(d0, 32); nu0 += __shfl_xor(nu0, 32);
    d1 += __shfl_xor(d1, 32); nu1 += __shfl_xor(nu1, 32);

    // per-b results: wave wv owns b = wv*64 + bs*32 + r (all m done inside wave)
    float* dsum = (float*)e_lds;          // 512 floats (e_lds dead after phase 1)
    float* nsum = dsum + 256;
    if (half == 0) {
        dsum[wv * 64 + r]      = d0; nsum[wv * 64 + r]      = nu0;
        dsum[wv * 64 + 32 + r] = d1; nsum[wv * 64 + 32 + r] = nu1;
    }
    __syncthreads();
    // BCE for b = t
    {
        float dd = dsum[t], nn = nsum[t];
        float p2 = nn / dd;
        p2 = fminf(fmaxf(p2, 1e-6f), 1.0f - 1e-6f);
        float tg = seq[(size_t)t * NPOS + n];
        float bce = (tg > 0.f) ? -logf(p2) : -logf(1.0f - p2);
#pragma unroll
        for (int o = 32; o; o >>= 1) bce += __shfl_xor(bce, o);
        if (lane == 0) z_lds[wv] = bce;   // z_lds reusable (rz consumed in epilogue)
    }
    __syncthreads();
    if (t == 0)
        atomicAdd(out, (z_lds[0] + z_lds[1] + z_lds[2] + z_lds[3]) * (1.0f / 130816.0f));
}

extern "C" void kernel_launch(void* const* d_in, const int* in_sizes, int n_in,
                              void* d_out, int out_size, void* d_ws, size_t ws_size,
                              hipStream_t stream) {
    const float* seq = (const float*)d_in[0];  // (B,N)
    const float* mem = (const float*)d_in[1];  // (M,N)
    const float* Al  = (const float*)d_in[2];  // (N,H,N)
    const float* Bl  = (const float*)d_in[3];  // (H,N)

    char* ws = (char*)d_ws;
    unsigned short* seq_bf = (unsigned short*)(ws + 0);          // 256 KB
    float*          BnT    = (float*)(ws + 262144);              // 128 KB (N,H)
    unsigned short* phimu  = (unsigned short*)(ws + 393216);     // 128 KB (M,H) *log2e
    float*          plusT  = (float*)(ws + 524288);              // 2 MB (N,M)
    float*          outp   = (float*)d_out;

    kA_prep<<<272, 256, 0, stream>>>(seq, Bl, mem, seq_bf, BnT, plusT, outp);
    k1b_phimu<<<512, 256, 0, stream>>>(BnT, mem, phimu);
    k23_fused<<<511, 256, 0, stream>>>(Al, seq_bf, phimu, plusT, seq, outp);
}